// Round 6
// baseline (2615.684 us; speedup 1.0000x reference)
//
#include <hip/hip_runtime.h>
#include <hip/hip_bf16.h>

#define NN 1024
#define BT 32
#define TT 32
#define NTOT 4588          // 32 diag + 496 tiles + 4060 phaseA WGs, topo order

// ---------------------------------------------------------------------------
// Fine-grained coherent (agent-scope, cache-bypassing) access helpers.
// ---------------------------------------------------------------------------
__device__ __forceinline__ double cload(const double* p) {
    return __hip_atomic_load(p, __ATOMIC_RELAXED, __HIP_MEMORY_SCOPE_AGENT);
}
__device__ __forceinline__ void cstore(double* p, double v) {
    __hip_atomic_store(p, v, __ATOMIC_RELAXED, __HIP_MEMORY_SCOPE_AGENT);
}
__device__ __forceinline__ void waitflag(const int* f, int a, int b) {
    const int* p = &f[(a * TT + b) << 4];
    while (!__hip_atomic_load(p, __ATOMIC_RELAXED, __HIP_MEMORY_SCOPE_AGENT))
        __builtin_amdgcn_s_sleep(1);
    __builtin_amdgcn_fence(__ATOMIC_ACQUIRE, "workgroup");   // compiler ordering only
}
__device__ __forceinline__ void setflag(int* f, int a, int b) {
    __hip_atomic_store(&f[(a * TT + b) << 4], 1, __ATOMIC_RELEASE, __HIP_MEMORY_SCOPE_AGENT);
}
__device__ __forceinline__ int tile_pidx(int I, int dd) {
    return dd * TT - (dd * (dd - 1)) / 2 + I;   // dense upper-tri index, dd-major
}

// ---------------------------------------------------------------------------
__global__ void primes_kernel(const float* __restrict__ feat, int* __restrict__ primes) {
    int i = blockIdx.x * blockDim.x + threadIdx.x;
    if (i < NN) {
        float best = feat[i * NN];
        int arg = 0;
        for (int ch = 1; ch < 4; ++ch) {
            float v = feat[ch * NN * NN + i * NN];
            if (v > best) { best = v; arg = ch; }
        }
        const int P[4] = {2, 3, 5, 7};
        primes[i] = P[arg];
    }
}

__global__ void prep_kernel(const float* __restrict__ con, const int* __restrict__ primes,
                            float* __restrict__ S, double* __restrict__ R,
                            double* __restrict__ C, float* __restrict__ out,
                            int* __restrict__ flags, int* __restrict__ done,
                            double* __restrict__ Pbuf) {
    int idx = blockIdx.x * blockDim.x + threadIdx.x;
    int i = idx >> 10;
    int j = idx & (NN - 1);
    float c = (con[idx] + con[j * NN + i]) * 0.5f;
    int prod = primes[i] * primes[j];
    bool canon = (prod == 14) | (prod == 15) | (prod == 35);
    int d = i - j; if (d < 0) d = -d;
    S[idx] = (canon && d >= 4) ? c : 0.0f;
    R[idx] = 0.0;
    C[idx] = 0.0;
    out[idx] = 0.0f;
    if (idx < TT * TT * 16) flags[idx] = 0;
    if (idx < 528 * 16) done[idx] = 0;
    if (idx < 528 * 1024) Pbuf[idx] = 0.0;
}

// ---------------------------------------------------------------------------
// 32x32x32 max-plus k-tile into P[16] regs (4x4 per lane). Single wave.
// ---------------------------------------------------------------------------
__device__ __forceinline__ void maxplus_ktile(const double* __restrict__ R,
                                              const double* __restrict__ C,
                                              double (*Ast)[34], double (*Bst)[34],
                                              double* P, int aI, int aJ, int kt0,
                                              int lane, int r4, int c4) {
    for (int w = 0; w < 16; ++w) {
        int idx = w * 64 + lane; int rr = idx >> 5, kk = idx & 31;
        Ast[kk][rr] = cload(&R[(aI + rr) * NN + kt0 + kk]);
        Bst[kk][rr] = cload(&C[(aJ + rr) * NN + kt0 + 1 + kk]);
    }
    for (int kk = 0; kk < 32; ++kk) {
        double2 av0 = *(const double2*)&Ast[kk][r4];
        double2 av1 = *(const double2*)&Ast[kk][r4 + 2];
        double2 bv0 = *(const double2*)&Bst[kk][c4];
        double2 bv1 = *(const double2*)&Bst[kk][c4 + 2];
        P[0]  = fmax(P[0],  av0.x + bv0.x); P[1]  = fmax(P[1],  av0.x + bv0.y);
        P[2]  = fmax(P[2],  av0.x + bv1.x); P[3]  = fmax(P[3],  av0.x + bv1.y);
        P[4]  = fmax(P[4],  av0.y + bv0.x); P[5]  = fmax(P[5],  av0.y + bv0.y);
        P[6]  = fmax(P[6],  av0.y + bv1.x); P[7]  = fmax(P[7],  av0.y + bv1.y);
        P[8]  = fmax(P[8],  av1.x + bv0.x); P[9]  = fmax(P[9],  av1.x + bv0.y);
        P[10] = fmax(P[10], av1.x + bv1.x); P[11] = fmax(P[11], av1.x + bv1.y);
        P[12] = fmax(P[12], av1.y + bv0.x); P[13] = fmax(P[13], av1.y + bv0.y);
        P[14] = fmax(P[14], av1.y + bv1.x); P[15] = fmax(P[15], av1.y + bv1.y);
    }
}

// ---------------------------------------------------------------------------
// Mega dataflow kernel: roles by topologically ordered blockIdx.
//   [32 diag] [31 tiles dd=1] [30 tiles dd=2]
//   then per dd=3..31: [(32-dd)(dd-3) phaseA] [(32-dd) tiles]
// Every candidate is one fp64 add of stored values (extras dominated) and
// fmax is order-insensitive => DP bitwise == numpy. Cross-WG data moves only
// through agent-coherent ops; no bulk cache fences anywhere.
// ---------------------------------------------------------------------------
__global__ __launch_bounds__(64) void nuss_df_kernel(double* __restrict__ R,
                                                     double* __restrict__ C,
                                                     const float* __restrict__ S,
                                                     int* __restrict__ flags,
                                                     int* __restrict__ done,
                                                     double* __restrict__ Pbuf) {
    // LDS regions (manual aliasing: Ast<->Vtc, Bst<->Pld)
    __shared__ __attribute__((aligned(16))) char lds[8704 + 8448 + 8704 + 4096 + 272];
    double (*Ast)[34]  = (double(*)[34])(lds);                    // 8704
    double (*Vtc)[33]  = (double(*)[33])(lds);                    // alias of Ast
    double (*DJJc)[33] = (double(*)[33])(lds + 8704);             // 8448
    double (*Bst)[34]  = (double(*)[34])(lds + 8704 + 8448);      // 8704
    double (*Pld)[33]  = (double(*)[33])(lds + 8704 + 8448);      // alias of Bst
    float  (*Sld)[32]  = (float(*)[32]) (lds + 8704 + 8448 + 8704);          // 4096
    double* edgeCol    = (double*)      (lds + 8704 + 8448 + 8704 + 4096);   // 264

    // ---- decode role ----
    int b = blockIdx.x;
    int role, I = 0, J = 0, t = 0, dd = 0;
    if (b < 32) { role = 0; I = b; }
    else {
        b -= 32;
        if (b < 31) { role = 1; dd = 1; I = b; J = I + 1; }
        else {
            b -= 31;
            if (b < 30) { role = 1; dd = 2; I = b; J = I + 2; }
            else {
                b -= 30;
                dd = 3;
                while (true) {
                    int ca = (TT - dd) * (dd - 3);
                    if (b < ca) { role = 2; I = b / (dd - 3); t = I + 2 + b % (dd - 3); J = I + dd; break; }
                    b -= ca;
                    int ct = TT - dd;
                    if (b < ct) { role = 1; I = b; J = I + dd; break; }
                    b -= ct; ++dd;
                }
            }
        }
    }
    const int lane = threadIdx.x;
    const int r = lane >> 1, h = lane & 1;
    const int r4 = (lane >> 3) * 4, c4 = (lane & 7) * 4;

    if (role == 2) {
        // ---------------- dedicated phaseA WG ----------------
        const int aI = I * BT, aJ = J * BT, kt0 = t * BT;
        waitflag(flags, I, t);
        waitflag(flags, t, J);
        double P[16];
        #pragma unroll
        for (int x = 0; x < 16; ++x) P[x] = 0.0;
        maxplus_ktile(R, C, Ast, Bst, P, aI, aJ, kt0, lane, r4, c4);
        const int pi = tile_pidx(I, dd);
        unsigned long long* Pb = (unsigned long long*)&Pbuf[(size_t)pi * 1024];
        #pragma unroll
        for (int x = 0; x < 4; ++x)
            #pragma unroll
            for (int y = 0; y < 4; ++y) {
                unsigned long long bits = (unsigned long long)__double_as_longlong(P[x * 4 + y]);
                atomicMax(&Pb[(r4 + x) * 32 + (c4 + y)], bits);
            }
        if (lane == 0)
            __hip_atomic_fetch_add(&done[pi * 16], 1, __ATOMIC_RELEASE, __HIP_MEMORY_SCOPE_AGENT);
        return;
    }

    if (role == 0) {
        // ---------------- diagonal tile ----------------
        const int aI = I * BT;
        for (int w = 0; w < 16; ++w) {
            int idx = w * 64 + lane; int rr = idx >> 5, cc = idx & 31;
            Sld[rr][cc] = S[(aI + rr) * NN + aI + cc];
        }
        for (int idx = lane; idx < 32 * 33; idx += 64)
            ((double*)Vtc)[idx] = 0.0;
        double vrow[16];
        #pragma unroll
        for (int u = 0; u < 16; ++u) vrow[u] = 0.0;
        for (int s = 1; s <= 31; ++s) {
            int c = r + s;
            bool act = (c <= 31);
            double acc = 0.0;
            if (act) {
                double t0 = 0.0, t1 = 0.0, t2 = 0.0, t3 = 0.0;
                #pragma unroll
                for (int u = 0; u < 16; u += 4) {
                    int k0 = h * 16 + u;
                    t0 = fmax(t0, vrow[u]     + Vtc[c][k0 + 1]);
                    t1 = fmax(t1, vrow[u + 1] + Vtc[c][k0 + 2]);
                    t2 = fmax(t2, vrow[u + 2] + Vtc[c][k0 + 3]);
                    t3 = fmax(t3, vrow[u + 3] + Vtc[c][k0 + 4]);
                }
                acc = fmax(fmax(t0, t1), fmax(t2, t3));
            }
            acc = fmax(acc, __shfl_xor(acc, 1));
            if (act) {
                double best = fmax(acc, Vtc[c - 1][r + 1] + (double)Sld[r][c]);
                if (h == 0) Vtc[c][r] = best;
                #pragma unroll
                for (int u = 0; u < 16; ++u)
                    if (h * 16 + u == c) vrow[u] = best;
            }
        }
        for (int w = 0; w < 16; ++w) {
            int idx = w * 64 + lane; int rr = idx >> 5, cc = idx & 31;
            cstore(&R[(aI + rr) * NN + aI + cc], Vtc[cc][rr]);
        }
        for (int w = 0; w < 16; ++w) {
            int idx = w * 64 + lane; int cc = idx >> 5, rr = idx & 31;
            cstore(&C[(aI + cc) * NN + aI + rr], Vtc[cc][rr]);
        }
        if (lane == 0) setflag(flags, I, I);
        return;
    }

    // ---------------- off-diagonal tile ----------------
    const int aI = I * BT, aJ = J * BT;
    const int pi = tile_pidx(I, dd);
    waitflag(flags, I, I);
    waitflag(flags, J, J);

    for (int w = 0; w < 16; ++w) {
        int idx = w * 64 + lane; int cc = idx >> 5, mm = idx & 31;
        DJJc[cc][mm] = cload(&C[(aJ + cc) * NN + aJ + mm]);
    }
    if (lane < 32) DJJc[lane][32] = 0.0;
    for (int w = 0; w < 16; ++w) {
        int idx = w * 64 + lane; int rr = idx >> 5, cc = idx & 31;
        Sld[rr][cc] = S[(aI + rr) * NN + aJ + cc];
    }
    double aslice[16];
    #pragma unroll
    for (int u = 0; u < 16; ++u) {
        int kk = h * 16 + u;
        aslice[u] = (kk >= r) ? cload(&R[(aI + r) * NN + aI + kk]) : -1.0e30;
    }

    // ---- stragglers (t = I+1 and t = J-1) computed in-wave ----
    double P[16];
    #pragma unroll
    for (int x = 0; x < 16; ++x) P[x] = 0.0;
    if (dd >= 2) {
        int t0 = I + 1, t1 = J - 1;
        waitflag(flags, I, t0);
        waitflag(flags, t0, J);
        maxplus_ktile(R, C, Ast, Bst, P, aI, aJ, t0 * BT, lane, r4, c4);
        if (t1 != t0) {
            waitflag(flags, I, t1);
            waitflag(flags, t1, J);
            maxplus_ktile(R, C, Ast, Bst, P, aI, aJ, t1 * BT, lane, r4, c4);
        }
    }

    // ---- interior contributions from dedicated phaseA WGs ----
    int need = (dd >= 4) ? dd - 3 : 0;
    if (need > 0) {
        const int* dp = &done[pi * 16];
        while (__hip_atomic_load(dp, __ATOMIC_RELAXED, __HIP_MEMORY_SCOPE_AGENT) < need)
            __builtin_amdgcn_s_sleep(1);
        __builtin_amdgcn_fence(__ATOMIC_ACQUIRE, "workgroup");
    }
    {
        const double* Pb = &Pbuf[(size_t)pi * 1024];
        #pragma unroll
        for (int x = 0; x < 4; ++x)
            #pragma unroll
            for (int y = 0; y < 4; ++y)
                P[x * 4 + y] = fmax(P[x * 4 + y], cload(&Pb[(r4 + x) * 32 + (c4 + y)]));
    }
    // write Pld (aliases Bst: last Bst use above)
    #pragma unroll
    for (int x = 0; x < 4; ++x)
        #pragma unroll
        for (int y = 0; y < 4; ++y)
            Pld[r4 + x][c4 + y] = P[x * 4 + y];

    // zero Vtc (aliases Ast: last Ast use above), then edges
    for (int idx = lane; idx < 32 * 33; idx += 64)
        ((double*)Vtc)[idx] = 0.0;
    if (lane < 33) edgeCol[lane] = cload(&R[(aI + lane) * NN + (aJ - 1)]);
    if (lane < 32) Vtc[lane][32] = cload(&R[(aI + 32) * NN + aJ + lane]);

    // ---- phaseB: 63 anti-diagonal micro-steps, barrier-free ----
    double vrow[16];
    #pragma unroll
    for (int u = 0; u < 16; ++u) vrow[u] = 0.0;
    for (int s = 0; s < 63; ++s) {
        int c = r + s - 31;
        bool act = ((unsigned)c < 32u);
        double acc = -1.0e30;
        if (act) {
            double t0 = -1.0e30, t1 = -1.0e30, t2 = -1.0e30, t3 = -1.0e30;
            #pragma unroll
            for (int u = 0; u < 16; u += 4) {
                int k0 = h * 16 + u;
                t0 = fmax(t0, aslice[u]     + Vtc[c][k0 + 1]);
                t1 = fmax(t1, aslice[u + 1] + Vtc[c][k0 + 2]);
                t2 = fmax(t2, aslice[u + 2] + Vtc[c][k0 + 3]);
                t3 = fmax(t3, aslice[u + 3] + Vtc[c][k0 + 4]);
            }
            double q0 = -1.0e30, q1 = -1.0e30, q2 = -1.0e30, q3 = -1.0e30;
            #pragma unroll
            for (int u = 0; u < 16; u += 4) {
                int m0 = h * 16 + u + 1;
                q0 = fmax(q0, vrow[u]     + DJJc[c][m0]);
                q1 = fmax(q1, vrow[u + 1] + DJJc[c][m0 + 1]);
                q2 = fmax(q2, vrow[u + 2] + DJJc[c][m0 + 2]);
                q3 = fmax(q3, vrow[u + 3] + DJJc[c][m0 + 3]);
            }
            acc = fmax(fmax(fmax(t0, t1), fmax(t2, t3)),
                       fmax(fmax(q0, q1), fmax(q2, q3)));
        }
        acc = fmax(acc, __shfl_xor(acc, 1));
        if (act) {
            double best = acc;
            best = fmax(best, edgeCol[r] + DJJc[c][0]);
            best = fmax(best, Pld[r][c]);
            double pv = (c > 0) ? Vtc[c - 1][r + 1] : edgeCol[r + 1];
            best = fmax(best, pv + (double)Sld[r][c]);
            if (h == 0) Vtc[c][r] = best;
            #pragma unroll
            for (int u = 0; u < 16; ++u)
                if (h * 16 + u == c) vrow[u] = best;
        }
    }

    for (int w = 0; w < 16; ++w) {
        int idx = w * 64 + lane; int rr = idx >> 5, cc = idx & 31;
        cstore(&R[(aI + rr) * NN + aJ + cc], Vtc[cc][rr]);
    }
    for (int w = 0; w < 16; ++w) {
        int idx = w * 64 + lane; int cc = idx >> 5, rr = idx & 31;
        cstore(&C[(aJ + cc) * NN + aI + rr], Vtc[cc][rr]);
    }
    if (lane == 0) setflag(flags, I, J);
}

// ---------------------------------------------------------------------------
// Traceback with band prefetch: stage a 16x17 R-patch + 16x16 S-patch per
// anchor, then walk up to 16 events from LDS with zero global latency.
// Decision sequence identical to the reference (same values, same eps).
// ---------------------------------------------------------------------------
__global__ __launch_bounds__(256) void traceback_kernel(const double* __restrict__ R,
                                                        const double* __restrict__ C,
                                                        const float* __restrict__ S,
                                                        float* __restrict__ out) {
    __shared__ int stk_i[2048];
    __shared__ int stk_j[2048];
    __shared__ double stk_v[2048];
    __shared__ double LR[16][17];
    __shared__ float  LS[16][16];
    __shared__ int sh_cmd, sh_i, sh_j, sh_top;
    __shared__ double sh_v;
    __shared__ double sred_v[4];
    __shared__ int sred_k[4];
    const double eps = 1e-9;
    int tid = threadIdx.x;
    if (tid == 0) {
        sh_top = 0; sh_i = 0; sh_j = NN - 1; sh_v = R[NN - 1]; sh_cmd = 0;
    }
    __syncthreads();
    while (true) {
        // stage band anchored at (sh_i, sh_j)
        int bi = sh_i, bj = sh_j;
        for (int idx = tid; idx < 16 * 17; idx += 256) {
            int t = idx / 17, w = idx % 17;
            int rr = bi + 1 + t; if (rr > NN - 1) rr = NN - 1;
            int cc = bj - 16 + w; if (cc < 0) cc = 0;
            LR[t][w] = R[rr * NN + cc];
        }
        {
            int t = tid >> 4, w = tid & 15;
            int rr = bi + t; if (rr > NN - 1) rr = NN - 1;
            int cc = bj - 15 + w; if (cc < 0) cc = 0;
            LS[t][w] = S[rr * NN + cc];
        }
        __syncthreads();
        if (tid == 0) {
            int i = sh_i, j = sh_j, top = sh_top, cmd;
            double v = sh_v;
            while (true) {
                if (j <= i || v <= eps) {
                    bool found = false;
                    while (top > 0) {
                        i = stk_i[--top]; j = stk_j[top]; v = stk_v[top];
                        if (j > i && v > eps) { found = true; break; }
                    }
                    if (!found) { cmd = 2; break; }
                }
                int t = i - bi, q = bj - j;
                if (t < 0 || t >= 16 || q < 0 || q > 15) { cmd = 0; break; }   // re-anchor
                double a  = LR[t][16 - q];
                double b2 = LR[t][15 - q];
                float  sv = LS[t][15 - q];
                if (a >= v - eps) { ++i; v = a; continue; }
                if (sv > 0.0f && b2 + (double)sv >= v - eps) {
                    out[i * NN + j] = sv; out[j * NN + i] = sv;
                    ++i; --j; v = b2; continue;
                }
                cmd = 1; break;    // split
            }
            sh_i = i; sh_j = j; sh_v = v; sh_top = top; sh_cmd = cmd;
        }
        __syncthreads();
        if (sh_cmd == 2) break;
        if (sh_cmd == 1) {
            int i = sh_i, j = sh_j;
            double bv = -1.0; int bk = 0x7fffffff;
            for (int k = i + tid; k < j; k += 256) {
                double tv = R[i * NN + k] + C[j * NN + k + 1];
                if (tv > bv) { bv = tv; bk = k; }
            }
            for (int off = 32; off; off >>= 1) {
                double ov = __shfl_down(bv, off);
                int    ok = __shfl_down(bk, off);
                if (ov > bv || (ov == bv && ok < bk)) { bv = ov; bk = ok; }
            }
            if ((tid & 63) == 0) { sred_v[tid >> 6] = bv; sred_k[tid >> 6] = bk; }
            __syncthreads();
            if (tid == 0) {
                double fv = sred_v[0]; int fk = sred_k[0];
                for (int w = 1; w < 4; ++w)
                    if (sred_v[w] > fv || (sred_v[w] == fv && sred_k[w] < fk)) { fv = sred_v[w]; fk = sred_k[w]; }
                int top = sh_top;
                stk_i[top] = sh_i; stk_j[top] = fk; stk_v[top] = R[sh_i * NN + fk]; ++top;  // pushed, popped later
                sh_top = top;
                sh_i = fk + 1;                      // continue with (k+1, j) = ref's next pop
                sh_v = R[(fk + 1) * NN + sh_j];
                sh_cmd = 0;
            }
            __syncthreads();
        }
    }
}

// ---------------------------------------------------------------------------
extern "C" void kernel_launch(void* const* d_in, const int* in_sizes, int n_in,
                              void* d_out, int out_size, void* d_ws, size_t ws_size,
                              hipStream_t stream) {
    const float* con  = (const float*)d_in[0];
    const float* feat = (const float*)d_in[1];
    float* out = (float*)d_out;

    char* ws = (char*)d_ws;
    double* R      = (double*)(ws);                                    // 8 MB
    double* C      = (double*)(ws + (size_t)8  * 1024 * 1024);         // 8 MB
    float*  S      = (float*) (ws + (size_t)16 * 1024 * 1024);         // 4 MB
    int*    primes = (int*)   (ws + (size_t)20 * 1024 * 1024);         // 4 KB
    int*    flags  = (int*)   (ws + (size_t)20 * 1024 * 1024 + 16384); // 64 KB
    int*    done   = (int*)   (ws + (size_t)20 * 1024 * 1024 + 98304); // 34 KB
    double* Pbuf   = (double*)(ws + (size_t)20 * 1024 * 1024 + 262144);// 4.33 MB

    primes_kernel<<<(NN + 255) / 256, 256, 0, stream>>>(feat, primes);
    prep_kernel<<<(NN * NN) / 256, 256, 0, stream>>>(con, primes, S, R, C, out,
                                                     flags, done, Pbuf);
    nuss_df_kernel<<<NTOT, 64, 0, stream>>>(R, C, S, flags, done, Pbuf);
    traceback_kernel<<<1, 256, 0, stream>>>(R, C, S, out);
}

// Round 7
// 2612.710 us; speedup vs baseline: 1.0011x; 1.0011x over previous
//
#include <hip/hip_runtime.h>
#include <hip/hip_bf16.h>

#define NN 1024
#define BT 32
#define TT 32
#define NTOT 4588          // 32 diag + 496 tiles + 4060 phaseA WGs, topo order

// ---------------------------------------------------------------------------
// Coherence model:
//  - producers: plain cached stores + ONE release (L2 writeback) via setflag
//  - consumers: relaxed agent-scope atomic loads (fresh at coherence point),
//    NO acquire fences -> zero L2 invalidates
// ---------------------------------------------------------------------------
__device__ __forceinline__ double cload(const double* p) {
    return __hip_atomic_load(p, __ATOMIC_RELAXED, __HIP_MEMORY_SCOPE_AGENT);
}
__device__ __forceinline__ void waitflag(const int* f, int a, int b) {
    const int* p = &f[(a * TT + b) << 4];
    while (!__hip_atomic_load(p, __ATOMIC_RELAXED, __HIP_MEMORY_SCOPE_AGENT))
        __builtin_amdgcn_s_sleep(4);
    __builtin_amdgcn_fence(__ATOMIC_ACQUIRE, "workgroup");   // compiler ordering only
}
__device__ __forceinline__ void setflag(int* f, int a, int b) {
    __hip_atomic_store(&f[(a * TT + b) << 4], 1, __ATOMIC_RELEASE, __HIP_MEMORY_SCOPE_AGENT);
}
__device__ __forceinline__ int tile_pidx(int I, int dd) {
    return dd * TT - (dd * (dd - 1)) / 2 + I;   // dense upper-tri index, dd-major
}

// ---------------------------------------------------------------------------
__global__ void primes_kernel(const float* __restrict__ feat, int* __restrict__ primes) {
    int i = blockIdx.x * blockDim.x + threadIdx.x;
    if (i < NN) {
        float best = feat[i * NN];
        int arg = 0;
        for (int ch = 1; ch < 4; ++ch) {
            float v = feat[ch * NN * NN + i * NN];
            if (v > best) { best = v; arg = ch; }
        }
        const int P[4] = {2, 3, 5, 7};
        primes[i] = P[arg];
    }
}

__global__ void prep_kernel(const float* __restrict__ con, const int* __restrict__ primes,
                            float* __restrict__ S, double* __restrict__ R,
                            double* __restrict__ C, float* __restrict__ out,
                            int* __restrict__ flags, int* __restrict__ done,
                            double* __restrict__ Pbuf) {
    int idx = blockIdx.x * blockDim.x + threadIdx.x;
    int i = idx >> 10;
    int j = idx & (NN - 1);
    float c = (con[idx] + con[j * NN + i]) * 0.5f;
    int prod = primes[i] * primes[j];
    bool canon = (prod == 14) | (prod == 15) | (prod == 35);
    int d = i - j; if (d < 0) d = -d;
    S[idx] = (canon && d >= 4) ? c : 0.0f;
    R[idx] = 0.0;
    C[idx] = 0.0;
    out[idx] = 0.0f;
    if (idx < TT * TT * 16) flags[idx] = 0;
    if (idx < 528 * 16) done[idx] = 0;
    if (idx < 528 * 1024) Pbuf[idx] = 0.0;
}

// ---------------------------------------------------------------------------
// 32x32x32 max-plus k-tile into P[16] regs (4x4 per lane). Single wave.
// ---------------------------------------------------------------------------
__device__ __forceinline__ void maxplus_ktile(const double* __restrict__ R,
                                              const double* __restrict__ C,
                                              double (*Ast)[34], double (*Bst)[34],
                                              double* P, int aI, int aJ, int kt0,
                                              int lane, int r4, int c4) {
    for (int w = 0; w < 16; ++w) {
        int idx = w * 64 + lane; int rr = idx >> 5, kk = idx & 31;
        Ast[kk][rr] = cload(&R[(aI + rr) * NN + kt0 + kk]);
        Bst[kk][rr] = cload(&C[(aJ + rr) * NN + kt0 + 1 + kk]);
    }
    for (int kk = 0; kk < 32; ++kk) {
        double2 av0 = *(const double2*)&Ast[kk][r4];
        double2 av1 = *(const double2*)&Ast[kk][r4 + 2];
        double2 bv0 = *(const double2*)&Bst[kk][c4];
        double2 bv1 = *(const double2*)&Bst[kk][c4 + 2];
        P[0]  = fmax(P[0],  av0.x + bv0.x); P[1]  = fmax(P[1],  av0.x + bv0.y);
        P[2]  = fmax(P[2],  av0.x + bv1.x); P[3]  = fmax(P[3],  av0.x + bv1.y);
        P[4]  = fmax(P[4],  av0.y + bv0.x); P[5]  = fmax(P[5],  av0.y + bv0.y);
        P[6]  = fmax(P[6],  av0.y + bv1.x); P[7]  = fmax(P[7],  av0.y + bv1.y);
        P[8]  = fmax(P[8],  av1.x + bv0.x); P[9]  = fmax(P[9],  av1.x + bv0.y);
        P[10] = fmax(P[10], av1.x + bv1.x); P[11] = fmax(P[11], av1.x + bv1.y);
        P[12] = fmax(P[12], av1.y + bv0.x); P[13] = fmax(P[13], av1.y + bv0.y);
        P[14] = fmax(P[14], av1.y + bv1.x); P[15] = fmax(P[15], av1.y + bv1.y);
    }
}

// ---------------------------------------------------------------------------
// Mega dataflow kernel (topo-ordered roles). Every candidate is one fp64 add
// of stored values (extras dominated); fmax order-insensitive => DP bitwise
// == numpy.
// ---------------------------------------------------------------------------
__global__ __launch_bounds__(64) void nuss_df_kernel(double* __restrict__ R,
                                                     double* __restrict__ C,
                                                     const float* __restrict__ S,
                                                     int* __restrict__ flags,
                                                     int* __restrict__ done,
                                                     double* __restrict__ Pbuf) {
    __shared__ __attribute__((aligned(16))) char lds[8704 + 8448 + 8704 + 4096 + 272];
    double (*Ast)[34]  = (double(*)[34])(lds);                    // 8704
    double (*Vtc)[33]  = (double(*)[33])(lds);                    // alias of Ast
    double (*DJJc)[33] = (double(*)[33])(lds + 8704);             // 8448
    double (*Bst)[34]  = (double(*)[34])(lds + 8704 + 8448);      // 8704
    double (*Pld)[33]  = (double(*)[33])(lds + 8704 + 8448);      // alias of Bst
    float  (*Sld)[32]  = (float(*)[32]) (lds + 8704 + 8448 + 8704);          // 4096
    double* edgeCol    = (double*)      (lds + 8704 + 8448 + 8704 + 4096);   // 264

    // ---- decode role ----
    int b = blockIdx.x;
    int role, I = 0, J = 0, t = 0, dd = 0;
    if (b < 32) { role = 0; I = b; }
    else {
        b -= 32;
        if (b < 31) { role = 1; dd = 1; I = b; J = I + 1; }
        else {
            b -= 31;
            if (b < 30) { role = 1; dd = 2; I = b; J = I + 2; }
            else {
                b -= 30;
                dd = 3;
                while (true) {
                    int ca = (TT - dd) * (dd - 3);
                    if (b < ca) { role = 2; I = b / (dd - 3); t = I + 2 + b % (dd - 3); J = I + dd; break; }
                    b -= ca;
                    int ct = TT - dd;
                    if (b < ct) { role = 1; I = b; J = I + dd; break; }
                    b -= ct; ++dd;
                }
            }
        }
    }
    const int lane = threadIdx.x;
    const int r = lane >> 1, h = lane & 1;
    const int r4 = (lane >> 3) * 4, c4 = (lane & 7) * 4;

    if (role == 2) {
        // ---------------- dedicated phaseA WG ----------------
        const int aI = I * BT, aJ = J * BT, kt0 = t * BT;
        waitflag(flags, I, t);
        waitflag(flags, t, J);
        double P[16];
        #pragma unroll
        for (int x = 0; x < 16; ++x) P[x] = 0.0;
        maxplus_ktile(R, C, Ast, Bst, P, aI, aJ, kt0, lane, r4, c4);
        const int pi = tile_pidx(I, dd);
        unsigned long long* Pb = (unsigned long long*)&Pbuf[(size_t)pi * 1024];
        #pragma unroll
        for (int x = 0; x < 4; ++x)
            #pragma unroll
            for (int y = 0; y < 4; ++y) {
                unsigned long long bits = (unsigned long long)__double_as_longlong(P[x * 4 + y]);
                atomicMax(&Pb[(r4 + x) * 32 + (c4 + y)], bits);
            }
        if (lane == 0)
            __hip_atomic_fetch_add(&done[pi * 16], 1, __ATOMIC_RELEASE, __HIP_MEMORY_SCOPE_AGENT);
        return;
    }

    if (role == 0) {
        // ---------------- diagonal tile ----------------
        const int aI = I * BT;
        for (int w = 0; w < 16; ++w) {
            int idx = w * 64 + lane; int rr = idx >> 5, cc = idx & 31;
            Sld[rr][cc] = S[(aI + rr) * NN + aI + cc];
        }
        for (int idx = lane; idx < 32 * 33; idx += 64)
            ((double*)Vtc)[idx] = 0.0;
        double vrow[16];
        #pragma unroll
        for (int u = 0; u < 16; ++u) vrow[u] = 0.0;
        for (int s = 1; s <= 31; ++s) {
            int c = r + s;
            bool act = (c <= 31);
            double acc = 0.0;
            if (act) {
                double t0 = 0.0, t1 = 0.0, t2 = 0.0, t3 = 0.0;
                #pragma unroll
                for (int u = 0; u < 16; u += 4) {
                    int k0 = h * 16 + u;
                    t0 = fmax(t0, vrow[u]     + Vtc[c][k0 + 1]);
                    t1 = fmax(t1, vrow[u + 1] + Vtc[c][k0 + 2]);
                    t2 = fmax(t2, vrow[u + 2] + Vtc[c][k0 + 3]);
                    t3 = fmax(t3, vrow[u + 3] + Vtc[c][k0 + 4]);
                }
                acc = fmax(fmax(t0, t1), fmax(t2, t3));
            }
            acc = fmax(acc, __shfl_xor(acc, 1));
            if (act) {
                double best = fmax(acc, Vtc[c - 1][r + 1] + (double)Sld[r][c]);
                if (h == 0) Vtc[c][r] = best;
                #pragma unroll
                for (int u = 0; u < 16; ++u)
                    if (h * 16 + u == c) vrow[u] = best;
            }
        }
        for (int w = 0; w < 16; ++w) {
            int idx = w * 64 + lane; int rr = idx >> 5, cc = idx & 31;
            R[(aI + rr) * NN + aI + cc] = Vtc[cc][rr];
        }
        for (int w = 0; w < 16; ++w) {
            int idx = w * 64 + lane; int cc = idx >> 5, rr = idx & 31;
            C[(aI + cc) * NN + aI + rr] = Vtc[cc][rr];
        }
        if (lane == 0) setflag(flags, I, I);   // release -> writeback + flag
        return;
    }

    // ---------------- off-diagonal tile ----------------
    const int aI = I * BT, aJ = J * BT;
    const int pi = tile_pidx(I, dd);
    waitflag(flags, I, I);
    waitflag(flags, J, J);

    for (int w = 0; w < 16; ++w) {
        int idx = w * 64 + lane; int cc = idx >> 5, mm = idx & 31;
        DJJc[cc][mm] = cload(&C[(aJ + cc) * NN + aJ + mm]);
    }
    if (lane < 32) DJJc[lane][32] = 0.0;
    for (int w = 0; w < 16; ++w) {
        int idx = w * 64 + lane; int rr = idx >> 5, cc = idx & 31;
        Sld[rr][cc] = S[(aI + rr) * NN + aJ + cc];
    }
    double aslice[16];
    #pragma unroll
    for (int u = 0; u < 16; ++u) {
        int kk = h * 16 + u;
        aslice[u] = (kk >= r) ? cload(&R[(aI + r) * NN + aI + kk]) : -1.0e30;
    }

    // ---- stragglers (t = I+1 and t = J-1) computed in-wave ----
    double P[16];
    #pragma unroll
    for (int x = 0; x < 16; ++x) P[x] = 0.0;
    if (dd >= 2) {
        int t0 = I + 1, t1 = J - 1;
        waitflag(flags, I, t0);
        waitflag(flags, t0, J);
        maxplus_ktile(R, C, Ast, Bst, P, aI, aJ, t0 * BT, lane, r4, c4);
        if (t1 != t0) {
            waitflag(flags, I, t1);
            waitflag(flags, t1, J);
            maxplus_ktile(R, C, Ast, Bst, P, aI, aJ, t1 * BT, lane, r4, c4);
        }
    }

    // ---- interior contributions from dedicated phaseA WGs ----
    int need = (dd >= 4) ? dd - 3 : 0;
    if (need > 0) {
        const int* dp = &done[pi * 16];
        while (__hip_atomic_load(dp, __ATOMIC_RELAXED, __HIP_MEMORY_SCOPE_AGENT) < need)
            __builtin_amdgcn_s_sleep(4);
        __builtin_amdgcn_fence(__ATOMIC_ACQUIRE, "workgroup");
    }
    {
        const double* Pb = &Pbuf[(size_t)pi * 1024];
        #pragma unroll
        for (int x = 0; x < 4; ++x)
            #pragma unroll
            for (int y = 0; y < 4; ++y)
                P[x * 4 + y] = fmax(P[x * 4 + y], cload(&Pb[(r4 + x) * 32 + (c4 + y)]));
    }
    #pragma unroll
    for (int x = 0; x < 4; ++x)
        #pragma unroll
        for (int y = 0; y < 4; ++y)
            Pld[r4 + x][c4 + y] = P[x * 4 + y];     // Pld aliases Bst (done with Bst)

    for (int idx = lane; idx < 32 * 33; idx += 64)
        ((double*)Vtc)[idx] = 0.0;                  // Vtc aliases Ast (done with Ast)
    if (lane < 33) edgeCol[lane] = cload(&R[(aI + lane) * NN + (aJ - 1)]);
    if (lane < 32) Vtc[lane][32] = cload(&R[(aI + 32) * NN + aJ + lane]);

    // ---- phaseB: 63 anti-diagonal micro-steps, barrier-free ----
    double vrow[16];
    #pragma unroll
    for (int u = 0; u < 16; ++u) vrow[u] = 0.0;
    for (int s = 0; s < 63; ++s) {
        int c = r + s - 31;
        bool act = ((unsigned)c < 32u);
        double acc = -1.0e30;
        if (act) {
            double t0 = -1.0e30, t1 = -1.0e30, t2 = -1.0e30, t3 = -1.0e30;
            #pragma unroll
            for (int u = 0; u < 16; u += 4) {
                int k0 = h * 16 + u;
                t0 = fmax(t0, aslice[u]     + Vtc[c][k0 + 1]);
                t1 = fmax(t1, aslice[u + 1] + Vtc[c][k0 + 2]);
                t2 = fmax(t2, aslice[u + 2] + Vtc[c][k0 + 3]);
                t3 = fmax(t3, aslice[u + 3] + Vtc[c][k0 + 4]);
            }
            double q0 = -1.0e30, q1 = -1.0e30, q2 = -1.0e30, q3 = -1.0e30;
            #pragma unroll
            for (int u = 0; u < 16; u += 4) {
                int m0 = h * 16 + u + 1;
                q0 = fmax(q0, vrow[u]     + DJJc[c][m0]);
                q1 = fmax(q1, vrow[u + 1] + DJJc[c][m0 + 1]);
                q2 = fmax(q2, vrow[u + 2] + DJJc[c][m0 + 2]);
                q3 = fmax(q3, vrow[u + 3] + DJJc[c][m0 + 3]);
            }
            acc = fmax(fmax(fmax(t0, t1), fmax(t2, t3)),
                       fmax(fmax(q0, q1), fmax(q2, q3)));
        }
        acc = fmax(acc, __shfl_xor(acc, 1));
        if (act) {
            double best = acc;
            best = fmax(best, edgeCol[r] + DJJc[c][0]);
            best = fmax(best, Pld[r][c]);
            double pv = (c > 0) ? Vtc[c - 1][r + 1] : edgeCol[r + 1];
            best = fmax(best, pv + (double)Sld[r][c]);
            if (h == 0) Vtc[c][r] = best;
            #pragma unroll
            for (int u = 0; u < 16; ++u)
                if (h * 16 + u == c) vrow[u] = best;
        }
    }

    for (int w = 0; w < 16; ++w) {
        int idx = w * 64 + lane; int rr = idx >> 5, cc = idx & 31;
        R[(aI + rr) * NN + aJ + cc] = Vtc[cc][rr];
    }
    for (int w = 0; w < 16; ++w) {
        int idx = w * 64 + lane; int cc = idx >> 5, rr = idx & 31;
        C[(aJ + cc) * NN + aI + rr] = Vtc[cc][rr];
    }
    if (lane == 0) setflag(flags, I, J);   // release -> writeback + flag
}

// ---------------------------------------------------------------------------
// Traceback with band prefetch (unchanged from R6 — passed bitwise).
// ---------------------------------------------------------------------------
__global__ __launch_bounds__(256) void traceback_kernel(const double* __restrict__ R,
                                                        const double* __restrict__ C,
                                                        const float* __restrict__ S,
                                                        float* __restrict__ out) {
    __shared__ int stk_i[2048];
    __shared__ int stk_j[2048];
    __shared__ double stk_v[2048];
    __shared__ double LR[16][17];
    __shared__ float  LS[16][16];
    __shared__ int sh_cmd, sh_i, sh_j, sh_top;
    __shared__ double sh_v;
    __shared__ double sred_v[4];
    __shared__ int sred_k[4];
    const double eps = 1e-9;
    int tid = threadIdx.x;
    if (tid == 0) {
        sh_top = 0; sh_i = 0; sh_j = NN - 1; sh_v = R[NN - 1]; sh_cmd = 0;
    }
    __syncthreads();
    while (true) {
        int bi = sh_i, bj = sh_j;
        for (int idx = tid; idx < 16 * 17; idx += 256) {
            int t = idx / 17, w = idx % 17;
            int rr = bi + 1 + t; if (rr > NN - 1) rr = NN - 1;
            int cc = bj - 16 + w; if (cc < 0) cc = 0;
            LR[t][w] = R[rr * NN + cc];
        }
        {
            int t = tid >> 4, w = tid & 15;
            int rr = bi + t; if (rr > NN - 1) rr = NN - 1;
            int cc = bj - 15 + w; if (cc < 0) cc = 0;
            LS[t][w] = S[rr * NN + cc];
        }
        __syncthreads();
        if (tid == 0) {
            int i = sh_i, j = sh_j, top = sh_top, cmd;
            double v = sh_v;
            while (true) {
                if (j <= i || v <= eps) {
                    bool found = false;
                    while (top > 0) {
                        i = stk_i[--top]; j = stk_j[top]; v = stk_v[top];
                        if (j > i && v > eps) { found = true; break; }
                    }
                    if (!found) { cmd = 2; break; }
                }
                int t = i - bi, q = bj - j;
                if (t < 0 || t >= 16 || q < 0 || q > 15) { cmd = 0; break; }
                double a  = LR[t][16 - q];
                double b2 = LR[t][15 - q];
                float  sv = LS[t][15 - q];
                if (a >= v - eps) { ++i; v = a; continue; }
                if (sv > 0.0f && b2 + (double)sv >= v - eps) {
                    out[i * NN + j] = sv; out[j * NN + i] = sv;
                    ++i; --j; v = b2; continue;
                }
                cmd = 1; break;
            }
            sh_i = i; sh_j = j; sh_v = v; sh_top = top; sh_cmd = cmd;
        }
        __syncthreads();
        if (sh_cmd == 2) break;
        if (sh_cmd == 1) {
            int i = sh_i, j = sh_j;
            double bv = -1.0; int bk = 0x7fffffff;
            for (int k = i + tid; k < j; k += 256) {
                double tv = R[i * NN + k] + C[j * NN + k + 1];
                if (tv > bv) { bv = tv; bk = k; }
            }
            for (int off = 32; off; off >>= 1) {
                double ov = __shfl_down(bv, off);
                int    ok = __shfl_down(bk, off);
                if (ov > bv || (ov == bv && ok < bk)) { bv = ov; bk = ok; }
            }
            if ((tid & 63) == 0) { sred_v[tid >> 6] = bv; sred_k[tid >> 6] = bk; }
            __syncthreads();
            if (tid == 0) {
                double fv = sred_v[0]; int fk = sred_k[0];
                for (int w = 1; w < 4; ++w)
                    if (sred_v[w] > fv || (sred_v[w] == fv && sred_k[w] < fk)) { fv = sred_v[w]; fk = sred_k[w]; }
                int top = sh_top;
                stk_i[top] = sh_i; stk_j[top] = fk; stk_v[top] = R[sh_i * NN + fk]; ++top;
                sh_top = top;
                sh_i = fk + 1;
                sh_v = R[(fk + 1) * NN + sh_j];
                sh_cmd = 0;
            }
            __syncthreads();
        }
    }
}

// ---------------------------------------------------------------------------
extern "C" void kernel_launch(void* const* d_in, const int* in_sizes, int n_in,
                              void* d_out, int out_size, void* d_ws, size_t ws_size,
                              hipStream_t stream) {
    const float* con  = (const float*)d_in[0];
    const float* feat = (const float*)d_in[1];
    float* out = (float*)d_out;

    char* ws = (char*)d_ws;
    double* R      = (double*)(ws);                                    // 8 MB
    double* C      = (double*)(ws + (size_t)8  * 1024 * 1024);         // 8 MB
    float*  S      = (float*) (ws + (size_t)16 * 1024 * 1024);         // 4 MB
    int*    primes = (int*)   (ws + (size_t)20 * 1024 * 1024);         // 4 KB
    int*    flags  = (int*)   (ws + (size_t)20 * 1024 * 1024 + 16384); // 64 KB
    int*    done   = (int*)   (ws + (size_t)20 * 1024 * 1024 + 98304); // 34 KB
    double* Pbuf   = (double*)(ws + (size_t)20 * 1024 * 1024 + 262144);// 4.33 MB

    primes_kernel<<<(NN + 255) / 256, 256, 0, stream>>>(feat, primes);
    prep_kernel<<<(NN * NN) / 256, 256, 0, stream>>>(con, primes, S, R, C, out,
                                                     flags, done, Pbuf);
    nuss_df_kernel<<<NTOT, 64, 0, stream>>>(R, C, S, flags, done, Pbuf);
    traceback_kernel<<<1, 256, 0, stream>>>(R, C, S, out);
}

// Round 8
// 2550.918 us; speedup vs baseline: 1.0254x; 1.0242x over previous
//
#include <hip/hip_runtime.h>
#include <hip/hip_bf16.h>

#define NN 1024
#define BT 32
#define TT 32
#define NTOT 934   // 32 diag + 496 tiles + 406 helpers, topo order

// flag kinds: 0=tile done, 1=pushR slice ready, 2=pushD slice ready, 3=helper done
__device__ __forceinline__ int tpidx(int I, int dd) { return dd * TT - (dd * (dd - 1)) / 2 + I; }
__device__ __forceinline__ void pollf(const int* f, int pidx, int kind) {
    const int* p = &f[pidx * 64 + kind * 16];
    while (!__hip_atomic_load(p, __ATOMIC_RELAXED, __HIP_MEMORY_SCOPE_AGENT))
        __builtin_amdgcn_s_sleep(1);
}
__device__ __forceinline__ void setf(int* f, int pidx, int kind) {
    __hip_atomic_store(&f[pidx * 64 + kind * 16], 1, __ATOMIC_RELAXED, __HIP_MEMORY_SCOPE_AGENT);
}
__device__ __forceinline__ void facq() { __builtin_amdgcn_fence(__ATOMIC_ACQUIRE, "agent"); }
__device__ __forceinline__ void frel() { __builtin_amdgcn_fence(__ATOMIC_RELEASE, "agent"); }

// ---------------------------------------------------------------------------
__global__ void primes_kernel(const float* __restrict__ feat, int* __restrict__ primes) {
    int i = blockIdx.x * blockDim.x + threadIdx.x;
    if (i < NN) {
        float best = feat[i * NN];
        int arg = 0;
        for (int ch = 1; ch < 4; ++ch) {
            float v = feat[ch * NN * NN + i * NN];
            if (v > best) { best = v; arg = ch; }
        }
        const int P[4] = {2, 3, 5, 7};
        primes[i] = P[arg];
    }
}

__global__ void prep_kernel(const float* __restrict__ con, const int* __restrict__ primes,
                            float* __restrict__ S, double* __restrict__ R,
                            double* __restrict__ C, float* __restrict__ out,
                            int* __restrict__ flags) {
    int idx = blockIdx.x * blockDim.x + threadIdx.x;
    int i = idx >> 10;
    int j = idx & (NN - 1);
    float c = (con[idx] + con[j * NN + i]) * 0.5f;
    int prod = primes[i] * primes[j];
    bool canon = (prod == 14) | (prod == 15) | (prod == 35);
    int d = i - j; if (d < 0) d = -d;
    S[idx] = (canon && d >= 4) ? c : 0.0f;
    R[idx] = 0.0;
    C[idx] = 0.0;
    out[idx] = 0.0f;
    if (idx < 528 * 64) flags[idx] = 0;
}

// ---------------------------------------------------------------------------
// Push-dataflow DP. Roles by topo blockIdx: [32 diag][per dd: helpers(dd>=4),
// tiles]. Every candidate is one fp64 add of stored values (extras dominated;
// fmax order-insensitive) => DP bitwise == numpy.
// ---------------------------------------------------------------------------
__global__ __launch_bounds__(64) void nuss_df_kernel(double* __restrict__ R,
                                                     double* __restrict__ C,
                                                     const float* __restrict__ S,
                                                     int* __restrict__ flags,
                                                     double* __restrict__ PRb,
                                                     double* __restrict__ PDb,
                                                     double* __restrict__ PHb) {
    __shared__ __attribute__((aligned(16))) char lds[38672];
    double (*Vtc)[33]  = (double(*)[33])(lds);              // 8448; col32 = edge row
    double (*DJJc)[33] = (double(*)[33])(lds + 8448);       // 8448
    float  (*Sld)[32]  = (float(*)[32]) (lds + 16896);      // 4096
    double* edgeCol    = (double*)      (lds + 20992);      // 264
    double (*Buf1)[34] = (double(*)[34])(lds + 21264);      // 8704
    double (*Pld)[33]  = (double(*)[33])(lds + 21264);      // alias of Buf1
    double (*Buf2)[34] = (double(*)[34])(lds + 29968);      // 8704

    // ---- decode role (topo order) ----
    int b = blockIdx.x;
    int role = 0, I = 0, J = 0, dd = 0;
    if (b < 32) { role = 0; I = b; J = b; }
    else {
        b -= 32; dd = 1;
        for (;;) {
            int nh = (dd >= 4) ? (TT - dd) : 0;
            if (b < nh) { role = 2; I = b; J = I + dd; break; }
            b -= nh;
            if (b < TT - dd) { role = 1; I = b; J = I + dd; break; }
            b -= TT - dd; ++dd;
        }
    }
    const int lane = threadIdx.x;
    const int r = lane >> 1, h = lane & 1;
    const int r4 = (lane >> 3) * 4, c4 = (lane & 7) * 4;

    if (role == 2) {
        // ---------------- helper: interior k-tiles, middle-out as-ready ----
        const int aI = I * BT, aJ = J * BT, pidx = tpidx(I, dd);
        double Q[16];
        #pragma unroll
        for (int x = 0; x < 16; ++x) Q[x] = 0.0;
        int nk2 = dd - 3;
        int tl = (I + J) >> 1, tr = tl + 1;
        for (int q = 0; q < nk2; ++q) {
            int t;
            if ((q & 1) == 0) { if (tl >= I + 2) t = tl--; else t = tr++; }
            else              { if (tr <= J - 2) t = tr++; else t = tl--; }
            pollf(flags, tpidx(I, t - I), 0);
            pollf(flags, tpidx(t, J - t), 0);
            pollf(flags, tpidx(t + 1, J - t - 1), 0);
            facq();
            for (int w = 0; w < 16; ++w) {
                int idx = w * 64 + lane; int rr = idx >> 5, kk = idx & 31;
                Buf1[kk][rr] = R[(aI + rr) * NN + t * BT + kk];
                Buf2[kk][rr] = C[(aJ + rr) * NN + t * BT + 1 + kk];
            }
            for (int kk = 0; kk < 32; ++kk) {
                double2 a0 = *(const double2*)&Buf1[kk][r4];
                double2 a1 = *(const double2*)&Buf1[kk][r4 + 2];
                double2 b0 = *(const double2*)&Buf2[kk][c4];
                double2 b1 = *(const double2*)&Buf2[kk][c4 + 2];
                Q[0]  = fmax(Q[0],  a0.x + b0.x); Q[1]  = fmax(Q[1],  a0.x + b0.y);
                Q[2]  = fmax(Q[2],  a0.x + b1.x); Q[3]  = fmax(Q[3],  a0.x + b1.y);
                Q[4]  = fmax(Q[4],  a0.y + b0.x); Q[5]  = fmax(Q[5],  a0.y + b0.y);
                Q[6]  = fmax(Q[6],  a0.y + b1.x); Q[7]  = fmax(Q[7],  a0.y + b1.y);
                Q[8]  = fmax(Q[8],  a1.x + b0.x); Q[9]  = fmax(Q[9],  a1.x + b0.y);
                Q[10] = fmax(Q[10], a1.x + b1.x); Q[11] = fmax(Q[11], a1.x + b1.y);
                Q[12] = fmax(Q[12], a1.y + b0.x); Q[13] = fmax(Q[13], a1.y + b0.y);
                Q[14] = fmax(Q[14], a1.y + b1.x); Q[15] = fmax(Q[15], a1.y + b1.y);
            }
        }
        double* dst = PHb + (size_t)pidx * 1024;
        #pragma unroll
        for (int x = 0; x < 4; ++x)
            #pragma unroll
            for (int y = 0; y < 4; ++y)
                dst[(r4 + x) * 32 + c4 + y] = Q[x * 4 + y];
        frel();
        if (lane == 0) setf(flags, pidx, 3);
        return;
    }

    if (role == 0) {
        // ---------------- diagonal tile ----------------
        const int aI = I * BT;
        for (int w = 0; w < 16; ++w) {
            int idx = w * 64 + lane; int rr = idx >> 5, cc = idx & 31;
            Sld[rr][cc] = S[(aI + rr) * NN + aI + cc];
        }
        for (int idx = lane; idx < 32 * 33; idx += 64)
            ((double*)Vtc)[idx] = 0.0;
        double vrow[16];
        #pragma unroll
        for (int u = 0; u < 16; ++u) vrow[u] = 0.0;
        for (int s = 1; s <= 31; ++s) {
            int c = r + s;
            bool act = (c <= 31);
            double acc = 0.0;
            if (act) {
                double t0 = 0.0, t1 = 0.0, t2 = 0.0, t3 = 0.0;
                #pragma unroll
                for (int u = 0; u < 16; u += 4) {
                    int k0 = h * 16 + u;
                    t0 = fmax(t0, vrow[u]     + Vtc[c][k0 + 1]);
                    t1 = fmax(t1, vrow[u + 1] + Vtc[c][k0 + 2]);
                    t2 = fmax(t2, vrow[u + 2] + Vtc[c][k0 + 3]);
                    t3 = fmax(t3, vrow[u + 3] + Vtc[c][k0 + 4]);
                }
                acc = fmax(fmax(t0, t1), fmax(t2, t3));
            }
            acc = fmax(acc, __shfl_xor(acc, 1));
            if (act) {
                double best = fmax(acc, Vtc[c - 1][r + 1] + (double)Sld[r][c]);
                if (h == 0) Vtc[c][r] = best;
                #pragma unroll
                for (int u = 0; u < 16; ++u)
                    if (h * 16 + u == c) vrow[u] = best;
            }
        }
        for (int w = 0; w < 16; ++w) {
            int idx = w * 64 + lane; int rr = idx >> 5, cc = idx & 31;
            R[(aI + rr) * NN + aI + cc] = Vtc[cc][rr];
        }
        for (int w = 0; w < 16; ++w) {
            int idx = w * 64 + lane; int cc = idx >> 5, rr = idx & 31;
            C[(aI + cc) * NN + aI + rr] = Vtc[cc][rr];
        }
        frel();
        if (lane == 0) setf(flags, I, 0);
        return;
    }

    // ---------------- off-diagonal tile ----------------
    const int aI = I * BT, aJ = J * BT, pidx = tpidx(I, dd);
    if (dd == 1) { pollf(flags, I, 0); pollf(flags, J, 0); }
    else {
        pollf(flags, pidx, 1);
        pollf(flags, pidx, 2);
        if (dd >= 4) pollf(flags, pidx, 3);
    }
    facq();   // the ONE critical-path acquire

    for (int w = 0; w < 16; ++w) {
        int idx = w * 64 + lane; int cc = idx >> 5, mm = idx & 31;
        DJJc[cc][mm] = C[(aJ + cc) * NN + aJ + mm];
    }
    if (lane < 32) DJJc[lane][32] = 0.0;
    for (int w = 0; w < 16; ++w) {
        int idx = w * 64 + lane; int rr = idx >> 5, cc = idx & 31;
        Sld[rr][cc] = S[(aI + rr) * NN + aJ + cc];
    }
    // fold push/helper slices -> Pld
    if (dd >= 2) {
        const double* SR = PRb + (size_t)pidx * 1024;
        const double* SD = PDb + (size_t)pidx * 1024;
        const double* SH = PHb + (size_t)pidx * 1024;
        for (int w = 0; w < 16; ++w) {
            int idx = w * 64 + lane; int rr = idx >> 5, cc = idx & 31;
            double p = fmax(SR[idx], SD[idx]);
            if (dd >= 4) p = fmax(p, SH[idx]);
            Pld[rr][cc] = p;
        }
    } else {
        for (int w = 0; w < 16; ++w) {
            int idx = w * 64 + lane; int rr = idx >> 5, cc = idx & 31;
            Pld[rr][cc] = 0.0;
        }
    }
    for (int idx = lane; idx < 32 * 33; idx += 64)
        ((double*)Vtc)[idx] = 0.0;
    if (lane < 33) edgeCol[lane] = R[(aI + lane) * NN + (aJ - 1)];
    if (lane < 32) Vtc[lane][32] = R[(aI + 32) * NN + aJ + lane];   // edge row
    double aslice[16];
    #pragma unroll
    for (int u = 0; u < 16; ++u) {
        int kk = h * 16 + u;
        aslice[u] = (kk >= r) ? R[(aI + r) * NN + aI + kk] : -1.0e30;
    }

    // ---- phaseB: 63 anti-diagonal micro-steps, barrier-free ----
    double vrow[16];
    #pragma unroll
    for (int u = 0; u < 16; ++u) vrow[u] = 0.0;
    for (int s = 0; s < 63; ++s) {
        int c = r + s - 31;
        bool act = ((unsigned)c < 32u);
        double acc = -1.0e30;
        if (act) {
            double t0 = -1.0e30, t1 = -1.0e30, t2 = -1.0e30, t3 = -1.0e30;
            #pragma unroll
            for (int u = 0; u < 16; u += 4) {
                int k0 = h * 16 + u;
                t0 = fmax(t0, aslice[u]     + Vtc[c][k0 + 1]);
                t1 = fmax(t1, aslice[u + 1] + Vtc[c][k0 + 2]);
                t2 = fmax(t2, aslice[u + 2] + Vtc[c][k0 + 3]);
                t3 = fmax(t3, aslice[u + 3] + Vtc[c][k0 + 4]);
            }
            double q0 = -1.0e30, q1 = -1.0e30, q2 = -1.0e30, q3 = -1.0e30;
            #pragma unroll
            for (int u = 0; u < 16; u += 4) {
                int m0 = h * 16 + u + 1;
                q0 = fmax(q0, vrow[u]     + DJJc[c][m0]);
                q1 = fmax(q1, vrow[u + 1] + DJJc[c][m0 + 1]);
                q2 = fmax(q2, vrow[u + 2] + DJJc[c][m0 + 2]);
                q3 = fmax(q3, vrow[u + 3] + DJJc[c][m0 + 3]);
            }
            acc = fmax(fmax(fmax(t0, t1), fmax(t2, t3)),
                       fmax(fmax(q0, q1), fmax(q2, q3)));
        }
        acc = fmax(acc, __shfl_xor(acc, 1));
        if (act) {
            double best = acc;
            best = fmax(best, edgeCol[r] + DJJc[c][0]);
            best = fmax(best, Pld[r][c]);
            double pv = (c > 0) ? Vtc[c - 1][r + 1] : edgeCol[r + 1];
            best = fmax(best, pv + (double)Sld[r][c]);
            if (h == 0) Vtc[c][r] = best;
            #pragma unroll
            for (int u = 0; u < 16; ++u)
                if (h * 16 + u == c) vrow[u] = best;
        }
    }

    for (int w = 0; w < 16; ++w) {
        int idx = w * 64 + lane; int rr = idx >> 5, cc = idx & 31;
        R[(aI + rr) * NN + aJ + cc] = Vtc[cc][rr];
    }
    for (int w = 0; w < 16; ++w) {
        int idx = w * 64 + lane; int cc = idx >> 5, rr = idx & 31;
        C[(aJ + cc) * NN + aI + rr] = Vtc[cc][rr];
    }
    frel();
    if (lane == 0) setf(flags, pidx, 0);   // done EARLY (before pushes; no cycles)

    // ---- pushes for right/down consumers ----
    bool doR = (J < 31), doD = (I > 0);
    if (doR) { pollf(flags, tpidx(J, 1), 0); pollf(flags, J + 1, 0); }
    if (doD) { pollf(flags, tpidx(I - 1, 1), 0); }
    if (doR || doD) facq();
    if (doR) {
        // G[kk][cc] = dp(aJ+1+kk, aJ+32+cc)  (tiles (J,J+1) + (J+1,J+1) row0)
        for (int w = 0; w < 16; ++w) {
            int idx = w * 64 + lane; int cc = idx >> 5, kk = idx & 31;
            Buf2[kk][cc] = C[(aJ + 32 + cc) * NN + (aJ + 1 + kk)];
        }
        double Q[16];
        #pragma unroll
        for (int x = 0; x < 16; ++x) Q[x] = 0.0;
        for (int kk = 0; kk < 32; ++kk) {
            double av[4];
            #pragma unroll
            for (int x = 0; x < 4; ++x) av[x] = Vtc[kk][r4 + x];   // W[r][kk]
            double2 b0 = *(const double2*)&Buf2[kk][c4];
            double2 b1 = *(const double2*)&Buf2[kk][c4 + 2];
            #pragma unroll
            for (int x = 0; x < 4; ++x) {
                Q[x * 4]     = fmax(Q[x * 4],     av[x] + b0.x);
                Q[x * 4 + 1] = fmax(Q[x * 4 + 1], av[x] + b0.y);
                Q[x * 4 + 2] = fmax(Q[x * 4 + 2], av[x] + b1.x);
                Q[x * 4 + 3] = fmax(Q[x * 4 + 3], av[x] + b1.y);
            }
        }
        double* dst = PRb + (size_t)tpidx(I, dd + 1) * 1024;
        #pragma unroll
        for (int x = 0; x < 4; ++x)
            #pragma unroll
            for (int y = 0; y < 4; ++y)
                dst[(r4 + x) * 32 + c4 + y] = Q[x * 4 + y];
    }
    if (doD) {
        // F[kk][cc] = dp(aI+1+kk, aJ+cc) from our tile (+edge row); H from (I-1,I)
        for (int w = 0; w < 16; ++w) {
            int idx = w * 64 + lane; int cc = idx >> 5, kk = idx & 31;
            Buf1[kk][cc] = (kk < 31) ? Vtc[cc][kk + 1] : Vtc[cc][32];
        }
        for (int w = 0; w < 16; ++w) {
            int idx = w * 64 + lane; int rr = idx >> 5, kk = idx & 31;
            Buf2[kk][rr] = R[((I - 1) * BT + rr) * NN + aI + kk];
        }
        double Q[16];
        #pragma unroll
        for (int x = 0; x < 16; ++x) Q[x] = 0.0;
        for (int kk = 0; kk < 32; ++kk) {
            double2 a0 = *(const double2*)&Buf2[kk][r4];
            double2 a1 = *(const double2*)&Buf2[kk][r4 + 2];
            double2 b0 = *(const double2*)&Buf1[kk][c4];
            double2 b1 = *(const double2*)&Buf1[kk][c4 + 2];
            Q[0]  = fmax(Q[0],  a0.x + b0.x); Q[1]  = fmax(Q[1],  a0.x + b0.y);
            Q[2]  = fmax(Q[2],  a0.x + b1.x); Q[3]  = fmax(Q[3],  a0.x + b1.y);
            Q[4]  = fmax(Q[4],  a0.y + b0.x); Q[5]  = fmax(Q[5],  a0.y + b0.y);
            Q[6]  = fmax(Q[6],  a0.y + b1.x); Q[7]  = fmax(Q[7],  a0.y + b1.y);
            Q[8]  = fmax(Q[8],  a1.x + b0.x); Q[9]  = fmax(Q[9],  a1.x + b0.y);
            Q[10] = fmax(Q[10], a1.x + b1.x); Q[11] = fmax(Q[11], a1.x + b1.y);
            Q[12] = fmax(Q[12], a1.y + b0.x); Q[13] = fmax(Q[13], a1.y + b0.y);
            Q[14] = fmax(Q[14], a1.y + b1.x); Q[15] = fmax(Q[15], a1.y + b1.y);
        }
        double* dst = PDb + (size_t)tpidx(I - 1, dd + 1) * 1024;
        #pragma unroll
        for (int x = 0; x < 4; ++x)
            #pragma unroll
            for (int y = 0; y < 4; ++y)
                dst[(r4 + x) * 32 + c4 + y] = Q[x * 4 + y];
    }
    if (doR || doD) {
        frel();
        if (lane == 0) {
            if (doR) setf(flags, tpidx(I, dd + 1), 1);
            if (doD) setf(flags, tpidx(I - 1, dd + 1), 2);
        }
    }
}

// ---------------------------------------------------------------------------
// Traceback with band prefetch (unchanged from R7 — bitwise-correct).
// ---------------------------------------------------------------------------
__global__ __launch_bounds__(256) void traceback_kernel(const double* __restrict__ R,
                                                        const double* __restrict__ C,
                                                        const float* __restrict__ S,
                                                        float* __restrict__ out) {
    __shared__ int stk_i[2048];
    __shared__ int stk_j[2048];
    __shared__ double stk_v[2048];
    __shared__ double LR[16][17];
    __shared__ float  LS[16][16];
    __shared__ int sh_cmd, sh_i, sh_j, sh_top;
    __shared__ double sh_v;
    __shared__ double sred_v[4];
    __shared__ int sred_k[4];
    const double eps = 1e-9;
    int tid = threadIdx.x;
    if (tid == 0) {
        sh_top = 0; sh_i = 0; sh_j = NN - 1; sh_v = R[NN - 1]; sh_cmd = 0;
    }
    __syncthreads();
    while (true) {
        int bi = sh_i, bj = sh_j;
        for (int idx = tid; idx < 16 * 17; idx += 256) {
            int t = idx / 17, w = idx % 17;
            int rr = bi + 1 + t; if (rr > NN - 1) rr = NN - 1;
            int cc = bj - 16 + w; if (cc < 0) cc = 0;
            LR[t][w] = R[rr * NN + cc];
        }
        {
            int t = tid >> 4, w = tid & 15;
            int rr = bi + t; if (rr > NN - 1) rr = NN - 1;
            int cc = bj - 15 + w; if (cc < 0) cc = 0;
            LS[t][w] = S[rr * NN + cc];
        }
        __syncthreads();
        if (tid == 0) {
            int i = sh_i, j = sh_j, top = sh_top, cmd;
            double v = sh_v;
            while (true) {
                if (j <= i || v <= eps) {
                    bool found = false;
                    while (top > 0) {
                        i = stk_i[--top]; j = stk_j[top]; v = stk_v[top];
                        if (j > i && v > eps) { found = true; break; }
                    }
                    if (!found) { cmd = 2; break; }
                }
                int t = i - bi, q = bj - j;
                if (t < 0 || t >= 16 || q < 0 || q > 15) { cmd = 0; break; }
                double a  = LR[t][16 - q];
                double b2 = LR[t][15 - q];
                float  sv = LS[t][15 - q];
                if (a >= v - eps) { ++i; v = a; continue; }
                if (sv > 0.0f && b2 + (double)sv >= v - eps) {
                    out[i * NN + j] = sv; out[j * NN + i] = sv;
                    ++i; --j; v = b2; continue;
                }
                cmd = 1; break;
            }
            sh_i = i; sh_j = j; sh_v = v; sh_top = top; sh_cmd = cmd;
        }
        __syncthreads();
        if (sh_cmd == 2) break;
        if (sh_cmd == 1) {
            int i = sh_i, j = sh_j;
            double bv = -1.0; int bk = 0x7fffffff;
            for (int k = i + tid; k < j; k += 256) {
                double tv = R[i * NN + k] + C[j * NN + k + 1];
                if (tv > bv) { bv = tv; bk = k; }
            }
            for (int off = 32; off; off >>= 1) {
                double ov = __shfl_down(bv, off);
                int    ok = __shfl_down(bk, off);
                if (ov > bv || (ov == bv && ok < bk)) { bv = ov; bk = ok; }
            }
            if ((tid & 63) == 0) { sred_v[tid >> 6] = bv; sred_k[tid >> 6] = bk; }
            __syncthreads();
            if (tid == 0) {
                double fv = sred_v[0]; int fk = sred_k[0];
                for (int w = 1; w < 4; ++w)
                    if (sred_v[w] > fv || (sred_v[w] == fv && sred_k[w] < fk)) { fv = sred_v[w]; fk = sred_k[w]; }
                int top = sh_top;
                stk_i[top] = sh_i; stk_j[top] = fk; stk_v[top] = R[sh_i * NN + fk]; ++top;
                sh_top = top;
                sh_i = fk + 1;
                sh_v = R[(fk + 1) * NN + sh_j];
                sh_cmd = 0;
            }
            __syncthreads();
        }
    }
}

// ---------------------------------------------------------------------------
extern "C" void kernel_launch(void* const* d_in, const int* in_sizes, int n_in,
                              void* d_out, int out_size, void* d_ws, size_t ws_size,
                              hipStream_t stream) {
    const float* con  = (const float*)d_in[0];
    const float* feat = (const float*)d_in[1];
    float* out = (float*)d_out;

    char* ws = (char*)d_ws;
    double* R      = (double*)(ws);                                     // 8 MB
    double* C      = (double*)(ws + (size_t)8  * 1024 * 1024);          // 8 MB
    float*  S      = (float*) (ws + (size_t)16 * 1024 * 1024);          // 4 MB
    int*    primes = (int*)   (ws + (size_t)20 * 1024 * 1024);          // 4 KB
    int*    flags  = (int*)   (ws + (size_t)20 * 1024 * 1024 + 16384);  // 135 KB
    double* PRb    = (double*)(ws + (size_t)21 * 1024 * 1024);          // 4.125 MB
    double* PDb    = (double*)(ws + (size_t)21 * 1024 * 1024 + 4325376);
    double* PHb    = (double*)(ws + (size_t)21 * 1024 * 1024 + 8650752);

    primes_kernel<<<(NN + 255) / 256, 256, 0, stream>>>(feat, primes);
    prep_kernel<<<(NN * NN) / 256, 256, 0, stream>>>(con, primes, S, R, C, out, flags);
    nuss_df_kernel<<<NTOT, 64, 0, stream>>>(R, C, S, flags, PRb, PDb, PHb);
    traceback_kernel<<<1, 256, 0, stream>>>(R, C, S, out);
}